// Round 4
// baseline (462.882 us; speedup 1.0000x reference)
//
#include <hip/hip_runtime.h>
#include <hip/hip_bf16.h>
#include <stdint.h>
#include <stddef.h>

// Problem constants
#define B_   2
#define L_   2048
#define E_   2048
#define H_   16
#define D_   128
#define F_   2048          // QKV_FEATURES
#define NROW (B_*L_)       // 4096
#define QS   6144          // fused qkv row stride (3*F_)

typedef __bf16 bf16_t;
typedef __bf16 bf16x4 __attribute__((ext_vector_type(4)));
typedef __bf16 bf16x8 __attribute__((ext_vector_type(8)));
typedef float  f32x4  __attribute__((ext_vector_type(4)));

// async global->LDS, 16B per lane. LDS dest = wave-uniform base + lane*16.
__device__ __forceinline__ void gload16(const void* g, void* l) {
  __builtin_amdgcn_global_load_lds(
      (const __attribute__((address_space(1))) void*)g,
      (__attribute__((address_space(3))) void*)l, 16, 0, 0);
}

// ---------------- fp32 -> bf16 elementwise ----------------
__global__ __launch_bounds__(256) void k_convert(const float* __restrict__ in,
                                                 bf16_t* __restrict__ out, int n4) {
  int i = blockIdx.x*256 + threadIdx.x;
  if (i >= n4) return;
  float4 v = ((const float4*)in)[i];
  bf16x4 t;
  t[0] = (__bf16)v.x; t[1] = (__bf16)v.y; t[2] = (__bf16)v.z; t[3] = (__bf16)v.w;
  ((bf16x4*)out)[i] = t;
}

// ------- transpose+convert: W[2048][2048] f32 -> WT[2048][2048] bf16 -------
__global__ __launch_bounds__(256) void k_transpose_w(const float* __restrict__ in,
                                                     bf16_t* __restrict__ out) {
  __shared__ float tile[32][33];
  const int ct = blockIdx.x, rt = blockIdx.y;
  const int c = threadIdx.x & 31, r0 = threadIdx.x >> 5;
  #pragma unroll
  for (int k = 0; k < 4; k++) {
    int r = r0 + k*8;
    tile[r][c] = in[(size_t)(rt*32 + r)*2048 + ct*32 + c];
  }
  __syncthreads();
  #pragma unroll
  for (int k = 0; k < 4; k++) {
    int r = r0 + k*8;
    out[(size_t)(ct*32 + r)*2048 + rt*32 + c] = (__bf16)tile[c][r];
  }
}

// ---------------- RoPE cos/sin table: [L][64] of float2(cos,sin) ----------------
__global__ __launch_bounds__(256) void k_sincos(float2* __restrict__ sc) {
  int id = blockIdx.x*256 + threadIdx.x;   // L_*64 threads
  int t = id >> 6, i = id & 63;
  float freq = powf(10000.0f, -(float)i / 64.0f);   // theta^(-2i/D)
  float a = (float)t * freq;
  sc[id] = make_float2(cosf(a), sinf(a));
}

// ---------------- in-place RoPE on bf16 slice of qkv [NROW][QS] ----------------
__global__ __launch_bounds__(256) void k_rope(bf16_t* __restrict__ qk,
                                              const float2* __restrict__ sc,
                                              float scale, int n4) {
  int i = blockIdx.x*256 + threadIdx.x;    // NROW*F_/4 groups (2 pairs each)
  if (i >= n4) return;
  int e  = i << 2;
  int d  = e & (F_-1);
  int ii = (d & (D_-1)) >> 1;              // pair index within head (even)
  int r  = e >> 11;                        // row (token) index
  int t  = r & (L_-1);                     // token position
  bf16_t* p = qk + (size_t)r*QS + d;
  bf16x4 v = *(const bf16x4*)p;
  float2 cs0 = sc[t*64 + ii];
  float2 cs1 = sc[t*64 + ii + 1];
  cs0.x *= scale; cs0.y *= scale; cs1.x *= scale; cs1.y *= scale;
  float x0 = (float)v[0], x1 = (float)v[1], x2 = (float)v[2], x3 = (float)v[3];
  bf16x4 o;
  o[0] = (__bf16)(x0*cs0.x - x1*cs0.y);
  o[1] = (__bf16)(x0*cs0.y + x1*cs0.x);
  o[2] = (__bf16)(x2*cs1.x - x3*cs1.y);
  o[3] = (__bf16)(x2*cs1.y + x3*cs1.x);
  *(bf16x4*)p = o;
}

// -------- transpose V: qkv v-slice [B*L][QS] bf16 -> Vt [B][H][D][L] bf16 --------
__global__ __launch_bounds__(256) void k_transpose_v(const bf16_t* __restrict__ in,
                                                     bf16_t* __restrict__ out) {
  __shared__ bf16_t tile[32][33];
  const int lt = blockIdx.x, dt = blockIdx.y, bh = blockIdx.z;
  const int b = bh >> 4;                   // H_=16
  const int h = bh & 15;
  const int c = threadIdx.x & 31, r0 = threadIdx.x >> 5;
  #pragma unroll
  for (int k = 0; k < 4; k++) {
    int r = r0 + k*8;
    tile[r][c] = in[(size_t)(b*L_ + lt*32 + r)*QS + h*D_ + dt*32 + c];
  }
  __syncthreads();
  #pragma unroll
  for (int k = 0; k < 4; k++) {
    int r = r0 + k*8;
    out[(size_t)(bh*D_ + dt*32 + r)*L_ + lt*32 + c] = tile[c][r];
  }
}

// ======== 256x256 8-phase counted-vmcnt GEMM (plain-HIP port of m201 schedule) ========
// C[M][N] = A[M][K] x BT[N][K], bf16 in, fp32 accum. BK=64, 512 thr (8 waves 2Mx4N).
// LDS 128KB: A[buf][half 128x64] at buf*32768+h*16384; B same at +65536.
// buf0 holds even K-tiles, buf1 odd. Stage ledger (iter i, phases 1..8):
//   ph1-3 stage tile(2i+1) halves A1,B0,B1 (A0 staged at ph8 of i-1); deadline ph5 via vmcnt(2)@ph4.
//   ph4-7 stage tile(2i+2) A0,A1,B0,B1 into buf0 (buf0 reads drained by ph3); deadline next ph1 via vmcnt(2)@ph8.
// Every stage into a region is issued after the barrier following that region's last read drain (WAR-safe);
// vmcnt(2) forces the upcoming tile fully landed while leaving 1 half-tile in flight (RAW-safe, never vmcnt(0)).
#define BAR_MID do { asm volatile("" ::: "memory"); __builtin_amdgcn_s_barrier(); \
  asm volatile("s_waitcnt lgkmcnt(0)" ::: "memory"); __builtin_amdgcn_sched_barrier(0); } while(0)
#define BAR_END do { asm volatile("" ::: "memory"); __builtin_amdgcn_s_barrier(); } while(0)
#define VMC(n)  asm volatile("s_waitcnt vmcnt(" #n ")" ::: "memory")

#define RDA03(BASE) do { _Pragma("unroll") for (int m_=0;m_<4;m_++) { \
  a[m_][0] = *(const bf16x8*)((BASE) + m_*2048 + cs0); \
  a[m_][1] = *(const bf16x8*)((BASE) + m_*2048 + cs1); } } while(0)
#define RDA47(BASE) do { _Pragma("unroll") for (int m_=0;m_<4;m_++) { \
  a[m_][0] = *(const bf16x8*)((BASE) + (m_+4)*2048 + cs0); \
  a[m_][1] = *(const bf16x8*)((BASE) + (m_+4)*2048 + cs1); } } while(0)
#define RDB01(BASE) do { _Pragma("unroll") for (int n_=0;n_<2;n_++) { \
  b[n_][0] = *(const bf16x8*)((BASE) + n_*2048 + cs0); \
  b[n_][1] = *(const bf16x8*)((BASE) + n_*2048 + cs1); } } while(0)
#define RDB23(BASE) do { _Pragma("unroll") for (int n_=0;n_<2;n_++) { \
  b[2+n_][0] = *(const bf16x8*)((BASE) + (2+n_)*2048 + cs0); \
  b[2+n_][1] = *(const bf16x8*)((BASE) + (2+n_)*2048 + cs1); } } while(0)
#define MM16(MB, NB) do { __builtin_amdgcn_s_setprio(1); \
  _Pragma("unroll") for (int m_=0;m_<4;m_++) { \
    _Pragma("unroll") for (int n_=0;n_<2;n_++) { \
      acc[(MB)+m_][(NB)+n_] = __builtin_amdgcn_mfma_f32_16x16x32_bf16(a[m_][0], b[(NB)+n_][0], acc[(MB)+m_][(NB)+n_], 0, 0, 0); \
      acc[(MB)+m_][(NB)+n_] = __builtin_amdgcn_mfma_f32_16x16x32_bf16(a[m_][1], b[(NB)+n_][1], acc[(MB)+m_][(NB)+n_], 0, 0, 0); } } \
  __builtin_amdgcn_s_setprio(0); } while(0)

template<typename OutT, bool BIAS>
__global__ __launch_bounds__(512, 1) void k_gemm256(const bf16_t* __restrict__ A,
                                                    const bf16_t* __restrict__ BT,
                                                    OutT* __restrict__ C,
                                                    const float* __restrict__ bias,
                                                    int M, int N, int K) {
  __shared__ char sm[131072];
  const int tid = threadIdx.x, lane = tid & 63, wave = tid >> 6;
  const int wr = wave >> 2, wc = wave & 3;
  const int lr = lane & 15, lg = lane >> 4;
  const int nbx = N >> 8, nwg = nbx * (M >> 8);
  int bid = blockIdx.x;
  const int cpx = nwg >> 3;
  bid = (bid & 7)*cpx + (bid >> 3);        // XCD swizzle (nwg % 8 == 0)
  const int bx = bid % nbx, by = bid / nbx;
  const int row0 = by << 8, col0 = bx << 8;
  // staging source (pre-swizzled 16B chunk so linear LDS dest lands swizzled)
  const int sr  = tid >> 3;                // 0..63
  const int sxe = ((tid & 7) ^ (sr & 7)) << 3;
  const bf16_t* Ag = A  + (size_t)(row0 + sr)*K + sxe;
  const bf16_t* Bg = BT + (size_t)(col0 + sr)*K + sxe;
  const uint32_t dst0 = wave*1024;
  auto stA = [&](int buf, int h, int kt) {
    const bf16_t* s = Ag + (size_t)(h*128)*K + kt;
    char* d = sm + buf*32768 + h*16384 + dst0;
    gload16(s, d); gload16(s + (size_t)64*K, d + 8192);
  };
  auto stB = [&](int buf, int h, int kt) {
    const bf16_t* s = Bg + (size_t)(h*128)*K + kt;
    char* d = sm + 65536 + buf*32768 + h*16384 + dst0;
    gload16(s, d); gload16(s + (size_t)64*K, d + 8192);
  };
  // frag-read bases: phys = row*128 + ((ks*4+lg)^(row&7))*16, row&7 == lr&7
  const int cs0 = ((lg)     ^ (lr & 7)) << 4;
  const int cs1 = ((4 + lg) ^ (lr & 7)) << 4;
  const char* A0 = sm +                     wr*16384 + lr*128;             // buf0 A(wr)
  const char* A1 = A0 + 32768;                                            // buf1
  const char* B0 = sm + 65536 + (wc >> 1)*16384 + ((wc & 1)*64 + lr)*128; // buf0 B
  const char* B1 = B0 + 32768;

  f32x4 acc[8][4] = {};
  bf16x8 a[4][2], b[4][2];

  // prologue: tile0 (buf0, 4 halves) + tile1.A0 (buf1)
  stA(0,0,0); stA(0,1,0); stB(0,0,0); stB(0,1,0); stA(1,0,64);
  VMC(2);                 // tile0 fully landed; tile1.A0 in flight
  BAR_END;

  const int Kc = K - 64;
  for (int kt0 = 0; kt0 < K; kt0 += 128) {
    const int kt1 = kt0 + 64;
    const int ktA = (kt0 + 128 < Kc) ? kt0 + 128 : Kc;   // tile 2i+2 (clamped tail)
    const int ktB = (kt0 + 192 < Kc) ? kt0 + 192 : Kc;   // tile 2i+3 (clamped tail)
    // ph1: Q(m0-3,n0-1) of even tile
    RDA03(A0); RDB01(B0); stA(1,1,kt1);
    BAR_MID; MM16(0,0); BAR_END;
    // ph2: Q(m0-3,n2-3)
    RDB23(B0); stB(1,0,kt1);
    BAR_MID; MM16(0,2); BAR_END;
    // ph3: Q(m4-7,n0-1)
    RDA47(A0); stB(1,1,kt1);
    BAR_MID; MM16(4,0); BAR_END;
    // ph4: Q(m4-7,n2-3); odd tile must be fully landed after this phase
    stA(0,0,ktA);
    BAR_MID; MM16(4,2); VMC(2); BAR_END;
    // ph5-8: odd tile (buf1)
    RDA03(A1); RDB01(B1); stA(0,1,ktA);
    BAR_MID; MM16(0,0); BAR_END;
    RDB23(B1); stB(0,0,ktA);
    BAR_MID; MM16(0,2); BAR_END;
    RDA47(A1); stB(0,1,ktA);
    BAR_MID; MM16(4,0); BAR_END;
    stA(1,0,ktB);
    BAR_MID; MM16(4,2); VMC(2); BAR_END;
  }
  VMC(0);
  // epilogue: C/D layout col=lane&15, row=(lane>>4)*4+j
  #pragma unroll
  for (int m = 0; m < 8; m++) {
    #pragma unroll
    for (int n = 0; n < 4; n++) {
      const int col = col0 + wc*64 + n*16 + lr;
      const float bv = BIAS ? bias[col] : 0.0f;
      #pragma unroll
      for (int j = 0; j < 4; j++) {
        const int row = row0 + wr*128 + m*16 + lg*4 + j;
        C[(size_t)row*N + col] = (OutT)(acc[m][n][j] + bv);
      }
    }
  }
}

// -------- Flash attention tile compute (swapped-operand form) --------
template<bool MASK>
__device__ __forceinline__ void attn_tile(
    int kv0, int wq0, int lr, int lg,
    const char* __restrict__ Kb, const char* __restrict__ Vb, char* __restrict__ Pb,
    const bf16x8 (&aq)[4], f32x4 (&o)[8], float& mrow, float& lsum) {
  const int swz = (lr & 7) << 4;
  // ---- S^T = K * Q^T ----
  f32x4 s[4] = {};
  #pragma unroll
  for (int kd = 0; kd < 4; kd++) {
    bf16x8 ak[4];
    #pragma unroll
    for (int n = 0; n < 4; n++)
      ak[n] = *(const bf16x8*)(Kb + (n*16 + lr)*256 + (((kd*4 + lg) << 4) ^ swz));
    __builtin_amdgcn_s_setprio(1);
    #pragma unroll
    for (int n = 0; n < 4; n++)
      s[n] = __builtin_amdgcn_mfma_f32_16x16x32_bf16(ak[n], aq[kd], s[n], 0, 0, 0);
    __builtin_amdgcn_s_setprio(0);
  }
  if (MASK) {
    const int q = wq0 + lr;
    #pragma unroll
    for (int n = 0; n < 4; n++)
      #pragma unroll
      for (int j = 0; j < 4; j++)
        if (kv0 + n*16 + lg*4 + j > q) s[n][j] = -30000.0f;
  }
  // ---- online softmax (lane owns one q-row; 2 shfl across lg groups) ----
  float pmax = fmaxf(
      fmaxf(fmaxf(fmaxf(s[0][0], s[0][1]), fmaxf(s[0][2], s[0][3])),
            fmaxf(fmaxf(s[1][0], s[1][1]), fmaxf(s[1][2], s[1][3]))),
      fmaxf(fmaxf(fmaxf(s[2][0], s[2][1]), fmaxf(s[2][2], s[2][3])),
            fmaxf(fmaxf(s[3][0], s[3][1]), fmaxf(s[3][2], s[3][3]))));
  pmax = fmaxf(pmax, __shfl_xor(pmax, 16));
  pmax = fmaxf(pmax, __shfl_xor(pmax, 32));
  if (!__all(pmax - mrow <= 8.0f)) {       // defer-max (T13)
    const float mnew = fmaxf(mrow, pmax);
    const float corr = exp2f(mrow - mnew);
    mrow = mnew;
    lsum *= corr;
    #pragma unroll
    for (int n2 = 0; n2 < 8; n2++) o[n2] *= corr;
  }
  float rs = 0.0f;
  #pragma unroll
  for (int n = 0; n < 4; n++)
    #pragma unroll
    for (int j = 0; j < 4; j++) {
      float p = exp2f(s[n][j] - mrow);
      s[n][j] = p;
      rs += p;
    }
  rs += __shfl_xor(rs, 16);
  rs += __shfl_xor(rs, 32);
  lsum += rs;
  // ---- P -> per-wave LDS [q=16][kv=64], swizzled 8B writes ----
  #pragma unroll
  for (int n = 0; n < 4; n++) {
    bf16x4 pw;
    pw[0] = (__bf16)s[n][0]; pw[1] = (__bf16)s[n][1];
    pw[2] = (__bf16)s[n][2]; pw[3] = (__bf16)s[n][3];
    *(bf16x4*)(Pb + ((lr*128 + n*32 + lg*8) ^ swz)) = pw;
  }
  // ---- O^T += V^T * P ----
  #pragma unroll
  for (int ks = 0; ks < 2; ks++) {
    bf16x8 pb = *(const bf16x8*)(Pb + ((lr*128 + ks*64 + lg*16) ^ swz));
    __builtin_amdgcn_s_setprio(1);
    #pragma unroll
    for (int n2 = 0; n2 < 8; n2++) {
      bf16x8 av = *(const bf16x8*)(Vb + (n2*16 + lr)*128 + (((ks*4 + lg) << 4) ^ swz));
      o[n2] = __builtin_amdgcn_mfma_f32_16x16x32_bf16(av, pb, o[n2], 0, 0, 0);
    }
    __builtin_amdgcn_s_setprio(0);
  }
}

// -------- Flash attention, causal. 8 waves x 16 q-rows. LDS 64KB -> 2 blocks/CU. --------
// K double-buffered via global_load_lds; V single-buffered via T14 async-split
// (global->reg at tile top overlapping compute, ds_write after the post-PV barrier).
__global__ __launch_bounds__(512, 4) void k_attn(const bf16_t* __restrict__ QKV,
                                                 const bf16_t* __restrict__ Vt,
                                                 bf16_t* __restrict__ O) {
  __shared__ bf16_t Ks[2][64*128];    // 16KB per buf
  __shared__ bf16_t Vs[128*64];       // 16KB, single buffer
  __shared__ bf16_t Pl[8][16*64];     // 2KB per wave
  const int tid = threadIdx.x, lane = tid & 63, wave = tid >> 6;
  const int qt = (int)gridDim.x - 1 - (int)blockIdx.x;   // heavy tiles first
  const int h = blockIdx.y, b = blockIdx.z;
  const int wq0 = qt*128 + wave*16;
  const int lr = lane & 15, lg = lane >> 4;
  char* Pb = (char*)&Pl[wave][0];
  const bf16_t* Q = QKV;
  const bf16_t* K = QKV + F_;

  bf16x8 aq[4];
  #pragma unroll
  for (int kd = 0; kd < 4; kd++)
    aq[kd] = *(const bf16x8*)&Q[(size_t)(b*L_ + wq0 + lr)*QS + h*D_ + kd*32 + lg*8];

  const int kr = tid >> 4, kc = tid & 15;
  const bf16_t* Kg0 = K + (size_t)(b*L_ + kr)*QS + h*D_ + ((kc ^ (kr & 7)) << 3);
  const int vr = tid >> 3, vc = tid & 7;
  const bf16_t* Vg0 = Vt + (size_t)((b*H_ + h)*D_ + vr)*L_ + ((vc ^ (vr & 7)) << 3);

  f32x4 o[8] = {};
  float mrow = -3.0e38f, lsum = 0.0f;
  const int ntb   = 2*qt + 2;
  const int nfull = (wq0 + 1) >> 6;
  const int nmine = ((wq0 + 15) >> 6) + 1;

  // prologue: stage K0 -> Ks[0], V0 -> Vs
  {
    char* kb = (char*)&Ks[0][0] + wave*1024;
    char* vb = (char*)Vs + wave*1024;
    gload16(Kg0,                 kb);
    gload16(Kg0 + (size_t)32*QS, kb + 8192);
    gload16(Vg0,                 vb);
    gload16(Vg0 + (size_t)64*L_, vb + 8192);
  }
  __syncthreads();

  int buf = 0;
  for (int t = 0; t < ntb; t++) {
    const bool pf = (t + 1 < ntb);
    bf16x8 v0, v1;
    if (pf) {                                  // K -> LDS (async), V -> regs (T14)
      const int kn = (t+1)*64;
      char* kb = (char*)&Ks[buf^1][0] + wave*1024;
      const bf16_t* kg = Kg0 + (size_t)kn*QS;
      gload16(kg,                 kb);
      gload16(kg + (size_t)32*QS, kb + 8192);
      v0 = *(const bf16x8*)(Vg0 + kn);
      v1 = *(const bf16x8*)(Vg0 + (size_t)64*L_ + kn);
    }
    if (t < nfull)
      attn_tile<false>(t*64, wq0, lr, lg, (const char*)&Ks[buf][0], (const char*)Vs, Pb, aq, o, mrow, lsum);
    else if (t < nmine)
      attn_tile<true >(t*64, wq0, lr, lg, (const char*)&Ks[buf][0], (const char*)Vs, Pb, aq, o, mrow, lsum);
    __syncthreads();                           // PV reads done; K-stage + V reg-loads drained
    if (pf) {
      *(bf16x8*)((char*)Vs + tid*16)        = v0;
      *(bf16x8*)((char*)Vs + 8192 + tid*16) = v1;
    }
    __syncthreads();                           // V ds_writes visible
    buf ^= 1;
  }
  const float inv = 1.0f / lsum;
  bf16_t* orow = O + (size_t)(b*L_ + wq0 + lr)*F_ + h*D_ + lg*4;
  #pragma unroll
  for (int n2 = 0; n2 < 8; n2++) {
    bf16x4 ov;
    ov[0] = (__bf16)(o[n2][0]*inv); ov[1] = (__bf16)(o[n2][1]*inv);
    ov[2] = (__bf16)(o[n2][2]*inv); ov[3] = (__bf16)(o[n2][3]*inv);
    *(bf16x4*)(orow + n2*16) = ov;
  }
}

extern "C" void kernel_launch(void* const* d_in, const int* in_sizes, int n_in,
                              void* d_out, int out_size, void* d_ws, size_t ws_size,
                              hipStream_t stream) {
  const float* x  = (const float*)d_in[0];
  const float* Wq = (const float*)d_in[1];
  const float* Wk = (const float*)d_in[2];
  const float* Wv = (const float*)d_in[3];
  const float* Wo = (const float*)d_in[4];
  const float* bo = (const float*)d_in[5];
  float* out = (float*)d_out;

  char* ws = (char*)d_ws;
  size_t off = 0;
  auto alloc = [&](size_t bytes) {
    char* p = ws + off;
    off = (off + bytes + 255) & ~(size_t)255;
    return p;
  };
  bf16_t* xb    = (bf16_t*)alloc((size_t)NROW*E_*2);     // x bf16; reused as attn out
  bf16_t* wqkvt = (bf16_t*)alloc((size_t)3*F_*E_*2);     // [Wq^T;Wk^T;Wv^T] bf16 [6144][2048]
  bf16_t* wot   = (bf16_t*)alloc((size_t)F_*E_*2);       // Wo^T bf16 [E][F]
  float2* sc    = (float2*)alloc((size_t)L_*64*sizeof(float2));
  bf16_t* qkv   = (bf16_t*)alloc((size_t)NROW*QS*2);     // fused QKV [4096][6144]
  bf16_t* vt    = (bf16_t*)alloc((size_t)NROW*F_*2);     // V^T [B][H][D][L]
  bf16_t* ob    = xb;                                    // attn output (xb dead by then)

  const float scale2 = 0.08838834764831845f * 1.44269504088896f;  // 1/sqrt(D) * log2(e)

  // 1. conversions / transposes / rope table
  k_convert<<<dim3((NROW*E_/4 + 255)/256), 256, 0, stream>>>(x, xb, NROW*E_/4);
  k_transpose_w<<<dim3(64, 64), 256, 0, stream>>>(Wq, wqkvt);
  k_transpose_w<<<dim3(64, 64), 256, 0, stream>>>(Wk, wqkvt + (size_t)F_*E_);
  k_transpose_w<<<dim3(64, 64), 256, 0, stream>>>(Wv, wqkvt + (size_t)2*F_*E_);
  k_transpose_w<<<dim3(64, 64), 256, 0, stream>>>(Wo, wot);
  k_sincos<<<dim3(L_*64/256), 256, 0, stream>>>(sc);

  // 2. fused QKV projection: [4096][2048] x [6144][2048]^T -> [4096][6144]
  k_gemm256<bf16_t, false><<<dim3((QS/256)*(NROW/256)), 512, 0, stream>>>(
      xb, wqkvt, qkv, nullptr, NROW, QS, E_);

  // 3. RoPE on Q (scale folded) and K slices; V transpose
  k_rope<<<dim3((NROW*F_/4 + 255)/256), 256, 0, stream>>>(qkv,      sc, scale2, NROW*F_/4);
  k_rope<<<dim3((NROW*F_/4 + 255)/256), 256, 0, stream>>>(qkv + F_, sc, 1.0f,   NROW*F_/4);
  k_transpose_v<<<dim3(L_/32, D_/32, B_*H_), 256, 0, stream>>>(qkv + 2*F_, vt);

  // 4. flash attention (writes ob = xb, bf16)
  k_attn<<<dim3(L_/128, H_, B_), 512, 0, stream>>>(qkv, vt, ob);

  // 5. output projection + bias (fp32 out)
  k_gemm256<float, true><<<dim3((E_/256)*(NROW/256)), 512, 0, stream>>>(
      ob, wot, out, bo, NROW, E_, F_);
}

// Round 5
// 443.291 us; speedup vs baseline: 1.0442x; 1.0442x over previous
//
#include <hip/hip_runtime.h>
#include <hip/hip_bf16.h>
#include <stdint.h>
#include <stddef.h>

// Problem constants
#define B_   2
#define L_   2048
#define E_   2048
#define H_   16
#define D_   128
#define F_   2048          // QKV_FEATURES
#define NROW (B_*L_)       // 4096
#define QS   6144          // fused qkv row stride (3*F_)

typedef __bf16 bf16_t;
typedef __bf16 bf16x4 __attribute__((ext_vector_type(4)));
typedef __bf16 bf16x8 __attribute__((ext_vector_type(8)));
typedef float  f32x4  __attribute__((ext_vector_type(4)));

// async global->LDS, 16B per lane. LDS dest = wave-uniform base + lane*16.
__device__ __forceinline__ void gload16(const void* g, void* l) {
  __builtin_amdgcn_global_load_lds(
      (const __attribute__((address_space(1))) void*)g,
      (__attribute__((address_space(3))) void*)l, 16, 0, 0);
}

#define VMC(n)  asm volatile("s_waitcnt vmcnt(" #n ")" ::: "memory")

// ---------------- fp32 -> bf16 elementwise ----------------
__global__ __launch_bounds__(256) void k_convert(const float* __restrict__ in,
                                                 bf16_t* __restrict__ out, int n4) {
  int i = blockIdx.x*256 + threadIdx.x;
  if (i >= n4) return;
  float4 v = ((const float4*)in)[i];
  bf16x4 t;
  t[0] = (__bf16)v.x; t[1] = (__bf16)v.y; t[2] = (__bf16)v.z; t[3] = (__bf16)v.w;
  ((bf16x4*)out)[i] = t;
}

// ------- transpose+convert all four weights in ONE launch (z selects matrix) -------
__global__ __launch_bounds__(256) void k_transpose_w4(const float* __restrict__ Wq,
                                                      const float* __restrict__ Wk,
                                                      const float* __restrict__ Wv,
                                                      const float* __restrict__ Wo,
                                                      bf16_t* __restrict__ wqkvt,
                                                      bf16_t* __restrict__ wot) {
  __shared__ float tile[32][33];
  const int z = blockIdx.z;
  const float* in = (z == 0) ? Wq : (z == 1) ? Wk : (z == 2) ? Wv : Wo;
  bf16_t* out = (z < 3) ? wqkvt + (size_t)z*F_*E_ : wot;
  const int ct = blockIdx.x, rt = blockIdx.y;
  const int c = threadIdx.x & 31, r0 = threadIdx.x >> 5;
  #pragma unroll
  for (int k = 0; k < 4; k++) {
    int r = r0 + k*8;
    tile[r][c] = in[(size_t)(rt*32 + r)*2048 + ct*32 + c];
  }
  __syncthreads();
  #pragma unroll
  for (int k = 0; k < 4; k++) {
    int r = r0 + k*8;
    out[(size_t)(ct*32 + r)*2048 + rt*32 + c] = (__bf16)tile[c][r];
  }
}

// ---------------- RoPE cos/sin table: [L][64] of float2(cos,sin) ----------------
__global__ __launch_bounds__(256) void k_sincos(float2* __restrict__ sc) {
  int id = blockIdx.x*256 + threadIdx.x;   // L_*64 threads
  int t = id >> 6, i = id & 63;
  float freq = powf(10000.0f, -(float)i / 64.0f);   // theta^(-2i/D)
  float a = (float)t * freq;
  sc[id] = make_float2(cosf(a), sinf(a));
}

// ------- in-place RoPE on BOTH q and k slices of qkv [NROW][QS], one launch -------
// q slice gets scale = 1/sqrt(D)*log2e folded in (f32, no extra bf16 rounding).
__global__ __launch_bounds__(256) void k_rope2(bf16_t* __restrict__ qkv,
                                               const float2* __restrict__ sc,
                                               float qscale, int half) {
  int i = blockIdx.x*256 + threadIdx.x;    // 0 .. 2*half-1
  const int part = (i >= half);            // 0 = q, 1 = k
  int j = part ? i - half : i;
  int e  = j << 2;
  int d  = e & (F_-1);
  int ii = (d & (D_-1)) >> 1;              // pair index within head (even)
  int r  = e >> 11;                        // row (token) index
  int t  = r & (L_-1);                     // token position
  bf16_t* p = qkv + (size_t)r*QS + part*F_ + d;
  const float scale = part ? 1.0f : qscale;
  bf16x4 v = *(const bf16x4*)p;
  float2 cs0 = sc[t*64 + ii];
  float2 cs1 = sc[t*64 + ii + 1];
  cs0.x *= scale; cs0.y *= scale; cs1.x *= scale; cs1.y *= scale;
  float x0 = (float)v[0], x1 = (float)v[1], x2 = (float)v[2], x3 = (float)v[3];
  bf16x4 o;
  o[0] = (__bf16)(x0*cs0.x - x1*cs0.y);
  o[1] = (__bf16)(x0*cs0.y + x1*cs0.x);
  o[2] = (__bf16)(x2*cs1.x - x3*cs1.y);
  o[3] = (__bf16)(x2*cs1.y + x3*cs1.x);
  *(bf16x4*)p = o;
}

// -------- transpose V: qkv v-slice [B*L][QS] bf16 -> Vt [B][H][D][L] bf16 --------
__global__ __launch_bounds__(256) void k_transpose_v(const bf16_t* __restrict__ in,
                                                     bf16_t* __restrict__ out) {
  __shared__ bf16_t tile[32][33];
  const int lt = blockIdx.x, dt = blockIdx.y, bh = blockIdx.z;
  const int b = bh >> 4;                   // H_=16
  const int h = bh & 15;
  const int c = threadIdx.x & 31, r0 = threadIdx.x >> 5;
  #pragma unroll
  for (int k = 0; k < 4; k++) {
    int r = r0 + k*8;
    tile[r][c] = in[(size_t)(b*L_ + lt*32 + r)*QS + h*D_ + dt*32 + c];
  }
  __syncthreads();
  #pragma unroll
  for (int k = 0; k < 4; k++) {
    int r = r0 + k*8;
    out[(size_t)(bh*D_ + dt*32 + r)*L_ + lt*32 + c] = tile[c][r];
  }
}

// ======== GEMM: C[M][N] = A[M][K] x BT[N][K], bf16 in, fp32 accum ========
// 128x128 tile, BK=32, 4 waves (2x2). 3-deep LDS pipeline (48KB -> 3 blocks/CU):
// stage tile t+2 at iter t => ~2 K-steps of flight before its vmcnt checkpoint
// (latency-robust counted-vmcnt, never vmcnt(0) until the tail). Raw s_barrier
// (no vmcnt drain in-loop). LDS 16B chunks XOR-swizzled by (row>>1)&3 via
// pre-swizzled global source (rule 21: same involution on stage and read).
template<typename OutT, bool BIAS>
__global__ __launch_bounds__(256, 3) void k_gemm_bt(const bf16_t* __restrict__ A,
                                                    const bf16_t* __restrict__ BT,
                                                    OutT* __restrict__ C,
                                                    const float* __restrict__ bias,
                                                    int M, int N, int K) {
  __shared__ char sm[49152];   // buf b at b*16384: A [128][32] then B [128][32]
  const int tid = threadIdx.x, lane = tid & 63, wave = tid >> 6;
  const int wr = wave >> 1, wc = wave & 1;
  const int lr = lane & 15, lg = lane >> 4;
  const int nbx = N >> 7, nwg = nbx * (M >> 7);
  int bid = blockIdx.x;
  const int cpx = nwg >> 3;
  bid = (bid & 7)*cpx + (bid >> 3);        // XCD swizzle (bijective: nwg % 8 == 0)
  const int bx = bid % nbx, by = bid / nbx;
  const int row0 = by << 7, col0 = bx << 7;
  // staging: thread tid covers row sr = tid>>2 (64 rows/instr), chunk tid&3.
  // source chunk pre-swizzled by (sr>>1)&3 so linear LDS dest lands swizzled.
  const int sr  = tid >> 2;
  const int sxe = (((tid & 3) ^ ((sr >> 1) & 3)) << 3);   // elems
  const bf16_t* Ag = A  + (size_t)(row0 + sr)*K + sxe;
  const bf16_t* Bg = BT + (size_t)(col0 + sr)*K + sxe;
  const int dst0 = wave*1024;
  auto stage = [&](int t) {
    char* base = sm + (t % 3)*16384;
    const bf16_t* a = Ag + t*32;
    const bf16_t* b = Bg + t*32;
    gload16(a,                base + dst0);
    gload16(a + (size_t)64*K, base + 4096  + dst0);
    gload16(b,                base + 8192  + dst0);
    gload16(b + (size_t)64*K, base + 12288 + dst0);
  };
  // frag reads: row r (r%16 == lr) at base + r*64 + ((lg ^ ((r>>1)&3))<<4)
  const int cs   = (lg ^ ((lr >> 1) & 3)) << 4;
  const int arow = (wr*64 + lr)*64;          // + m*1024
  const int brow = 8192 + (wc*64 + lr)*64;   // + n*1024
  f32x4 acc[4][4] = {};
  stage(0); stage(1);
  const int nt = K >> 5;
  for (int t = 0; t < nt; t++) {
    if (t + 2 < nt)      { stage(t + 2); VMC(8); }  // tile t drained; t+1,t+2 in flight
    else if (t + 1 < nt) { VMC(4); }
    else                 { VMC(0); }
    __builtin_amdgcn_s_barrier();            // all waves' tile-t slices landed
    const char* base = sm + (t % 3)*16384;
    bf16x8 af[4], bb[4];
    #pragma unroll
    for (int m = 0; m < 4; m++) af[m] = *(const bf16x8*)(base + arow + m*1024 + cs);
    #pragma unroll
    for (int n = 0; n < 4; n++) bb[n] = *(const bf16x8*)(base + brow + n*1024 + cs);
    asm volatile("s_waitcnt lgkmcnt(0)" ::: "memory");
    __builtin_amdgcn_sched_barrier(0);
    __builtin_amdgcn_s_setprio(1);
    #pragma unroll
    for (int m = 0; m < 4; m++)
      #pragma unroll
      for (int n = 0; n < 4; n++)
        acc[m][n] = __builtin_amdgcn_mfma_f32_16x16x32_bf16(af[m], bb[n], acc[m][n], 0, 0, 0);
    __builtin_amdgcn_s_setprio(0);
    __builtin_amdgcn_s_barrier();            // reads of buf t done -> overwritable
  }
  // epilogue: C/D layout col=lane&15, row=(lane>>4)*4+j (m89-verified)
  #pragma unroll
  for (int m = 0; m < 4; m++) {
    #pragma unroll
    for (int n = 0; n < 4; n++) {
      const int col = col0 + wc*64 + n*16 + lr;
      const float bv = BIAS ? bias[col] : 0.0f;
      #pragma unroll
      for (int j = 0; j < 4; j++) {
        const int row = row0 + wr*64 + m*16 + lg*4 + j;
        C[(size_t)row*N + col] = (OutT)(acc[m][n][j] + bv);
      }
    }
  }
}

// -------- Flash attention tile compute (swapped-operand form) --------
// Lane (lr,lg): q-row = wq0+lr; S^T[kv=n*16+lg*4+j][q=lr]. Scores arrive
// pre-scaled by 1/sqrt(D)*log2e (folded into Q's RoPE) -> exp2f softmax.
template<bool MASK>
__device__ __forceinline__ void attn_tile(
    int kv0, int wq0, int lr, int lg,
    const char* __restrict__ Kb, const char* __restrict__ Vb, char* __restrict__ Pb,
    const bf16x8 (&aq)[4], f32x4 (&o)[8], float& mrow, float& lsum) {
  const int swz = (lr & 7) << 4;
  // ---- S^T = K * Q^T ----
  f32x4 s[4] = {};
  #pragma unroll
  for (int kd = 0; kd < 4; kd++) {
    bf16x8 ak[4];
    #pragma unroll
    for (int n = 0; n < 4; n++)
      ak[n] = *(const bf16x8*)(Kb + (n*16 + lr)*256 + (((kd*4 + lg) << 4) ^ swz));
    __builtin_amdgcn_s_setprio(1);
    #pragma unroll
    for (int n = 0; n < 4; n++)
      s[n] = __builtin_amdgcn_mfma_f32_16x16x32_bf16(ak[n], aq[kd], s[n], 0, 0, 0);
    __builtin_amdgcn_s_setprio(0);
  }
  if (MASK) {
    const int q = wq0 + lr;
    #pragma unroll
    for (int n = 0; n < 4; n++)
      #pragma unroll
      for (int j = 0; j < 4; j++)
        if (kv0 + n*16 + lg*4 + j > q) s[n][j] = -30000.0f;
  }
  // ---- online softmax (lane owns one q-row; 2 shfl across lg groups) ----
  float pmax = fmaxf(
      fmaxf(fmaxf(fmaxf(s[0][0], s[0][1]), fmaxf(s[0][2], s[0][3])),
            fmaxf(fmaxf(s[1][0], s[1][1]), fmaxf(s[1][2], s[1][3]))),
      fmaxf(fmaxf(fmaxf(s[2][0], s[2][1]), fmaxf(s[2][2], s[2][3])),
            fmaxf(fmaxf(s[3][0], s[3][1]), fmaxf(s[3][2], s[3][3]))));
  pmax = fmaxf(pmax, __shfl_xor(pmax, 16));
  pmax = fmaxf(pmax, __shfl_xor(pmax, 32));
  if (!__all(pmax - mrow <= 8.0f)) {       // defer-max (T13)
    const float mnew = fmaxf(mrow, pmax);
    const float corr = exp2f(mrow - mnew);
    mrow = mnew;
    lsum *= corr;
    #pragma unroll
    for (int n2 = 0; n2 < 8; n2++) o[n2] *= corr;
  }
  float rs = 0.0f;
  #pragma unroll
  for (int n = 0; n < 4; n++)
    #pragma unroll
    for (int j = 0; j < 4; j++) {
      float p = exp2f(s[n][j] - mrow);
      s[n][j] = p;
      rs += p;
    }
  rs += __shfl_xor(rs, 16);
  rs += __shfl_xor(rs, 32);
  lsum += rs;
  // ---- P -> per-wave LDS [q=16][kv=64], swizzled 8B writes ----
  #pragma unroll
  for (int n = 0; n < 4; n++) {
    bf16x4 pw;
    pw[0] = (__bf16)s[n][0]; pw[1] = (__bf16)s[n][1];
    pw[2] = (__bf16)s[n][2]; pw[3] = (__bf16)s[n][3];
    *(bf16x4*)(Pb + ((lr*128 + n*32 + lg*8) ^ swz)) = pw;
  }
  // ---- O^T += V^T * P ----
  #pragma unroll
  for (int ks = 0; ks < 2; ks++) {
    bf16x8 pb = *(const bf16x8*)(Pb + ((lr*128 + ks*64 + lg*16) ^ swz));
    __builtin_amdgcn_s_setprio(1);
    #pragma unroll
    for (int n2 = 0; n2 < 8; n2++) {
      bf16x8 av = *(const bf16x8*)(Vb + (n2*16 + lr)*128 + (((ks*4 + lg) << 4) ^ swz));
      o[n2] = __builtin_amdgcn_mfma_f32_16x16x32_bf16(av, pb, o[n2], 0, 0, 0);
    }
    __builtin_amdgcn_s_setprio(0);
  }
}

// -------- Flash attention, causal. 8 waves x 16 q-rows = 128 q-rows/block. --------
// (r3 version, proven 123.7us) K/V^T LDS-staged dbuf via global_load_lds,
// pre-swizzled source; full/boundary tile split; one __syncthreads per tile.
__global__ __launch_bounds__(512, 4) void k_attn(const bf16_t* __restrict__ QKV,
                                                 const bf16_t* __restrict__ Vt,
                                                 bf16_t* __restrict__ O) {
  __shared__ bf16_t Ks[2][64*128];    // 16KB each buf
  __shared__ bf16_t Vs[2][128*64];    // 16KB each buf
  __shared__ bf16_t Pl[8][16*64];     // 2KB per wave
  const int tid = threadIdx.x, lane = tid & 63, wave = tid >> 6;
  const int qt = (int)gridDim.x - 1 - (int)blockIdx.x;   // heavy tiles first
  const int h = blockIdx.y, b = blockIdx.z;
  const int wq0 = qt*128 + wave*16;
  const int lr = lane & 15, lg = lane >> 4;
  char* Pb = (char*)&Pl[wave][0];
  const bf16_t* Q = QKV;
  const bf16_t* K = QKV + F_;

  bf16x8 aq[4];
  #pragma unroll
  for (int kd = 0; kd < 4; kd++)
    aq[kd] = *(const bf16x8*)&Q[(size_t)(b*L_ + wq0 + lr)*QS + h*D_ + kd*32 + lg*8];

  const int kr = tid >> 4, kc = tid & 15;
  const bf16_t* Kg0 = K + (size_t)(b*L_ + kr)*QS + h*D_ + ((kc ^ (kr & 7)) << 3);
  const int vr = tid >> 3, vc = tid & 7;
  const bf16_t* Vg0 = Vt + (size_t)((b*H_ + h)*D_ + vr)*L_ + ((vc ^ (vr & 7)) << 3);

  f32x4 o[8] = {};
  float mrow = -3.0e38f, lsum = 0.0f;
  const int ntb   = 2*qt + 2;                 // block covers kv < (qt+1)*128
  const int nfull = (wq0 + 1) >> 6;           // fully-unmasked tiles for this wave
  const int nmine = ((wq0 + 15) >> 6) + 1;    // tiles this wave computes

  // prologue: stage tile 0
  {
    char* kb = (char*)&Ks[0][0] + wave*1024;
    char* vb = (char*)&Vs[0][0] + wave*1024;
    gload16(Kg0,                 kb);
    gload16(Kg0 + (size_t)32*QS, kb + 8192);
    gload16(Vg0,                 vb);
    gload16(Vg0 + (size_t)64*L_, vb + 8192);
  }
  __syncthreads();

  int buf = 0;
  for (int t = 0; t < ntb; t++) {
    if (t + 1 < ntb) {                         // async stage next tile
      const int kn = (t+1)*64;
      char* kb = (char*)&Ks[buf^1][0] + wave*1024;
      char* vb = (char*)&Vs[buf^1][0] + wave*1024;
      const bf16_t* kg = Kg0 + (size_t)kn*QS;
      const bf16_t* vg = Vg0 + kn;
      gload16(kg,                 kb);
      gload16(kg + (size_t)32*QS, kb + 8192);
      gload16(vg,                 vb);
      gload16(vg + (size_t)64*L_, vb + 8192);
    }
    const char* Kb = (const char*)&Ks[buf][0];
    const char* Vb = (const char*)&Vs[buf][0];
    if (t < nfull)
      attn_tile<false>(t*64, wq0, lr, lg, Kb, Vb, Pb, aq, o, mrow, lsum);
    else if (t < nmine)
      attn_tile<true >(t*64, wq0, lr, lg, Kb, Vb, Pb, aq, o, mrow, lsum);
    __syncthreads();                           // drains stage; all waves done with buf
    buf ^= 1;
  }
  const float inv = 1.0f / lsum;
  bf16_t* orow = O + (size_t)(b*L_ + wq0 + lr)*F_ + h*D_ + lg*4;
  #pragma unroll
  for (int n2 = 0; n2 < 8; n2++) {
    bf16x4 ov;
    ov[0] = (__bf16)(o[n2][0]*inv); ov[1] = (__bf16)(o[n2][1]*inv);
    ov[2] = (__bf16)(o[n2][2]*inv); ov[3] = (__bf16)(o[n2][3]*inv);
    *(bf16x4*)(orow + n2*16) = ov;
  }
}

extern "C" void kernel_launch(void* const* d_in, const int* in_sizes, int n_in,
                              void* d_out, int out_size, void* d_ws, size_t ws_size,
                              hipStream_t stream) {
  const float* x  = (const float*)d_in[0];
  const float* Wq = (const float*)d_in[1];
  const float* Wk = (const float*)d_in[2];
  const float* Wv = (const float*)d_in[3];
  const float* Wo = (const float*)d_in[4];
  const float* bo = (const float*)d_in[5];
  float* out = (float*)d_out;

  char* ws = (char*)d_ws;
  size_t off = 0;
  auto alloc = [&](size_t bytes) {
    char* p = ws + off;
    off = (off + bytes + 255) & ~(size_t)255;
    return p;
  };
  bf16_t* xb    = (bf16_t*)alloc((size_t)NROW*E_*2);     // x bf16; reused as attn out
  bf16_t* wqkvt = (bf16_t*)alloc((size_t)3*F_*E_*2);     // [Wq^T;Wk^T;Wv^T] bf16 [6144][2048]
  bf16_t* wot   = (bf16_t*)alloc((size_t)F_*E_*2);       // Wo^T bf16 [E][F]
  float2* sc    = (float2*)alloc((size_t)L_*64*sizeof(float2));
  bf16_t* qkv   = (bf16_t*)alloc((size_t)NROW*QS*2);     // fused QKV [4096][6144]
  bf16_t* vt    = (bf16_t*)alloc((size_t)NROW*F_*2);     // V^T [B][H][D][L]
  bf16_t* ob    = xb;                                    // attn output (xb dead by then)

  const float scale2 = 0.08838834764831845f * 1.44269504088896f;  // 1/sqrt(D) * log2(e)

  // 1. conversions / transposes / rope table
  k_convert<<<dim3((NROW*E_/4 + 255)/256), 256, 0, stream>>>(x, xb, NROW*E_/4);
  k_transpose_w4<<<dim3(64, 64, 4), 256, 0, stream>>>(Wq, Wk, Wv, Wo, wqkvt, wot);
  k_sincos<<<dim3(L_*64/256), 256, 0, stream>>>(sc);

  // 2. fused QKV projection: [4096][2048] x [6144][2048]^T -> [4096][6144]
  k_gemm_bt<bf16_t, false><<<dim3((QS/128)*(NROW/128)), 256, 0, stream>>>(
      xb, wqkvt, qkv, nullptr, NROW, QS, E_);

  // 3. RoPE on Q (scale folded) + K in one launch; V transpose
  k_rope2<<<dim3(2*(NROW*F_/4)/256), 256, 0, stream>>>(qkv, sc, scale2, NROW*F_/4);
  k_transpose_v<<<dim3(L_/32, D_/32, B_*H_), 256, 0, stream>>>(qkv + 2*F_, vt);

  // 4. flash attention (writes ob = xb, bf16)
  k_attn<<<dim3(L_/128, H_, B_), 512, 0, stream>>>(qkv, vt, ob);

  // 5. output projection + bias (fp32 out)
  k_gemm_bt<float, true><<<dim3((E_/128)*(NROW/128)), 256, 0, stream>>>(
      ob, wot, out, bo, NROW, E_, F_);
}

// Round 6
// 402.248 us; speedup vs baseline: 1.1507x; 1.1020x over previous
//
#include <hip/hip_runtime.h>
#include <hip/hip_bf16.h>
#include <stdint.h>
#include <stddef.h>

// Problem constants
#define B_   2
#define L_   2048
#define E_   2048
#define H_   16
#define D_   128
#define F_   2048          // QKV_FEATURES
#define NROW (B_*L_)       // 4096
#define QS   6144          // fused qkv row stride (3*F_)

typedef __bf16 bf16_t;
typedef __bf16 bf16x4 __attribute__((ext_vector_type(4)));
typedef __bf16 bf16x8 __attribute__((ext_vector_type(8)));
typedef float  f32x4  __attribute__((ext_vector_type(4)));

// async global->LDS, 16B per lane. LDS dest = wave-uniform base + lane*16.
__device__ __forceinline__ void gload16(const void* g, void* l) {
  __builtin_amdgcn_global_load_lds(
      (const __attribute__((address_space(1))) void*)g,
      (__attribute__((address_space(3))) void*)l, 16, 0, 0);
}

#define VMC(n)  asm volatile("s_waitcnt vmcnt(" #n ")" ::: "memory")
#define BAR_MID do { asm volatile("" ::: "memory"); __builtin_amdgcn_s_barrier(); \
  asm volatile("s_waitcnt lgkmcnt(0)" ::: "memory"); __builtin_amdgcn_sched_barrier(0); } while(0)
#define BAR_END do { asm volatile("" ::: "memory"); __builtin_amdgcn_s_barrier(); } while(0)

// ---------------- fused prep: x->bf16 | 4x W transpose+convert | sincos table ----------------
__global__ __launch_bounds__(256) void k_prep(const float* __restrict__ x,
                                              const float* __restrict__ Wq,
                                              const float* __restrict__ Wk,
                                              const float* __restrict__ Wv,
                                              const float* __restrict__ Wo,
                                              bf16_t* __restrict__ xb,
                                              bf16_t* __restrict__ wqkvt,
                                              bf16_t* __restrict__ wot,
                                              float2* __restrict__ sc) {
  const int bb = blockIdx.x;
  if (bb < 8192) {                       // convert x (NROW*E_/4 = 2M float4 groups)
    int i = bb*256 + threadIdx.x;
    float4 v = ((const float4*)x)[i];
    bf16x4 t;
    t[0] = (__bf16)v.x; t[1] = (__bf16)v.y; t[2] = (__bf16)v.z; t[3] = (__bf16)v.w;
    ((bf16x4*)xb)[i] = t;
  } else if (bb < 24576) {               // weight transposes (64x64 tiles x 4 mats)
    __shared__ float tile[32][33];
    const int r4 = bb - 8192;
    const int z  = r4 >> 12;
    const int xy = r4 & 4095;
    const int ct = xy & 63, rt = xy >> 6;
    const float* in = (z == 0) ? Wq : (z == 1) ? Wk : (z == 2) ? Wv : Wo;
    bf16_t* out = (z < 3) ? wqkvt + (size_t)z*F_*E_ : wot;
    const int c = threadIdx.x & 31, r0 = threadIdx.x >> 5;
    #pragma unroll
    for (int k = 0; k < 4; k++) {
      int r = r0 + k*8;
      tile[r][c] = in[(size_t)(rt*32 + r)*2048 + ct*32 + c];
    }
    __syncthreads();
    #pragma unroll
    for (int k = 0; k < 4; k++) {
      int r = r0 + k*8;
      out[(size_t)(ct*32 + r)*2048 + rt*32 + c] = (__bf16)tile[c][r];
    }
  } else {                               // sincos table (L_*64 entries)
    int id = (bb - 24576)*256 + threadIdx.x;
    int t = id >> 6, i = id & 63;
    float freq = powf(10000.0f, -(float)i / 64.0f);
    float a = (float)t * freq;
    sc[id] = make_float2(cosf(a), sinf(a));
  }
}

// ------- fused: RoPE on q,k slices of qkv | V transpose to Vt [B][H][D][L] -------
__global__ __launch_bounds__(256) void k_ropetv(bf16_t* __restrict__ qkv,
                                                bf16_t* __restrict__ vt,
                                                const float2* __restrict__ sc,
                                                float qscale) {
  const int bb = blockIdx.x;
  if (bb < 16384) {                      // RoPE: 2*(NROW*F_/4) lanes
    const int half = NROW*F_/4;
    int i = bb*256 + threadIdx.x;
    const int part = (i >= half);        // 0 = q, 1 = k
    int j = part ? i - half : i;
    int e  = j << 2;
    int d  = e & (F_-1);
    int ii = (d & (D_-1)) >> 1;
    int r  = e >> 11;
    int t  = r & (L_-1);
    bf16_t* p = qkv + (size_t)r*QS + part*F_ + d;
    const float scale = part ? 1.0f : qscale;
    bf16x4 v = *(const bf16x4*)p;
    float2 cs0 = sc[t*64 + ii];
    float2 cs1 = sc[t*64 + ii + 1];
    cs0.x *= scale; cs0.y *= scale; cs1.x *= scale; cs1.y *= scale;
    float x0 = (float)v[0], x1 = (float)v[1], x2 = (float)v[2], x3 = (float)v[3];
    bf16x4 o;
    o[0] = (__bf16)(x0*cs0.x - x1*cs0.y);
    o[1] = (__bf16)(x0*cs0.y + x1*cs0.x);
    o[2] = (__bf16)(x2*cs1.x - x3*cs1.y);
    o[3] = (__bf16)(x2*cs1.y + x3*cs1.x);
    *(bf16x4*)p = o;
  } else {                               // V transpose: 8192 blocks
    __shared__ bf16_t tile[32][33];
    const int r8 = bb - 16384;
    const int lt = r8 & 63, dt = (r8 >> 6) & 3, bh = r8 >> 8;
    const int b = bh >> 4, h = bh & 15;
    const int c = threadIdx.x & 31, r0 = threadIdx.x >> 5;
    #pragma unroll
    for (int k = 0; k < 4; k++) {
      int r = r0 + k*8;
      tile[r][c] = qkv[(size_t)(b*L_ + lt*32 + r)*QS + 2*F_ + h*D_ + dt*32 + c];
    }
    __syncthreads();
    #pragma unroll
    for (int k = 0; k < 4; k++) {
      int r = r0 + k*8;
      vt[(size_t)(bh*D_ + dt*32 + r)*L_ + lt*32 + c] = tile[c][r];
    }
  }
}

// ======== 256x256 4-phase counted-vmcnt GEMM (corrected ledger) ========
// C[M][N] = A[M][K] x BT[N][K], bf16, fp32 accum. BK=64, 512 thr (8 waves 2Mx4N).
// LDS 128KB: A buf b half h at b*32768+h*16384; B same at +65536. Tile u -> buf u&1.
// Per group u (4 phases): reads ph1: A(m0-3)+B(n0-1); ph2: B(n2-3); ph3: A(m4-7).
// Stages: ph1: A1(u+1)->buf^1; ph3: B0,B1(u+2)->buf; ph4: A0(u+2)->buf.
// All WAR-safe (each region staged the phase after its last ds_read drains).
// vmcnt(6) at ph4 drains exactly tile u+1 (14 outstanding -> 6 = B0,B1,A0(u+2));
// min 3-phase flight per half-tile. Tail: last two groups use vmcnt(0).
// Column-band XCD map: XCD x owns bx in [x*band, x*band+band) -> B panels L2-hot.
#define RDA03(BASE) do { _Pragma("unroll") for (int m_=0;m_<4;m_++) { \
  a[m_][0] = *(const bf16x8*)((BASE) + m_*2048 + cs0); \
  a[m_][1] = *(const bf16x8*)((BASE) + m_*2048 + cs1); } } while(0)
#define RDA47(BASE) do { _Pragma("unroll") for (int m_=0;m_<4;m_++) { \
  a[m_][0] = *(const bf16x8*)((BASE) + (m_+4)*2048 + cs0); \
  a[m_][1] = *(const bf16x8*)((BASE) + (m_+4)*2048 + cs1); } } while(0)
#define RDB01(BASE) do { _Pragma("unroll") for (int n_=0;n_<2;n_++) { \
  b[n_][0] = *(const bf16x8*)((BASE) + n_*2048 + cs0); \
  b[n_][1] = *(const bf16x8*)((BASE) + n_*2048 + cs1); } } while(0)
#define RDB23(BASE) do { _Pragma("unroll") for (int n_=0;n_<2;n_++) { \
  b[2+n_][0] = *(const bf16x8*)((BASE) + (2+n_)*2048 + cs0); \
  b[2+n_][1] = *(const bf16x8*)((BASE) + (2+n_)*2048 + cs1); } } while(0)
#define MM16(MB, NB) do { __builtin_amdgcn_s_setprio(1); \
  _Pragma("unroll") for (int m_=0;m_<4;m_++) { \
    _Pragma("unroll") for (int n_=0;n_<2;n_++) { \
      acc[(MB)+m_][(NB)+n_] = __builtin_amdgcn_mfma_f32_16x16x32_bf16(a[m_][0], b[(NB)+n_][0], acc[(MB)+m_][(NB)+n_], 0, 0, 0); \
      acc[(MB)+m_][(NB)+n_] = __builtin_amdgcn_mfma_f32_16x16x32_bf16(a[m_][1], b[(NB)+n_][1], acc[(MB)+m_][(NB)+n_], 0, 0, 0); } } \
  __builtin_amdgcn_s_setprio(0); } while(0)

template<typename OutT, bool BIAS>
__global__ __launch_bounds__(512, 1) void k_gemm256(const bf16_t* __restrict__ A,
                                                    const bf16_t* __restrict__ BT,
                                                    OutT* __restrict__ C,
                                                    const float* __restrict__ bias,
                                                    int M, int N, int K) {
  __shared__ char sm[131072];
  const int tid = threadIdx.x, lane = tid & 63, wave = tid >> 6;
  const int wr = wave >> 2, wc = wave & 3;
  const int lr = lane & 15, lg = lane >> 4;
  const int nbx = N >> 8;
  const int band = nbx >> 3;               // requires nbx % 8 == 0
  const int bid = blockIdx.x;
  const int idx = bid >> 3;
  const int bx = (bid & 7)*band + idx % band;
  const int by = idx / band;
  const int row0 = by << 8, col0 = bx << 8;
  // staging source (pre-swizzled 16B chunk so linear LDS dest lands swizzled)
  const int sr  = tid >> 3;                // 0..63
  const int sxe = ((tid & 7) ^ (sr & 7)) << 3;
  const bf16_t* Ag = A  + (size_t)(row0 + sr)*K + sxe;
  const bf16_t* Bg = BT + (size_t)(col0 + sr)*K + sxe;
  char* smA = sm;
  char* smB = sm + 65536;
  const int dst0 = wave*1024;
  auto stA = [&](int buf, int h, int kt) {
    const bf16_t* s = Ag + (size_t)(h*128)*K + kt;
    char* d = smA + buf*32768 + h*16384 + dst0;
    gload16(s, d); gload16(s + (size_t)64*K, d + 8192);
  };
  auto stB = [&](int buf, int h, int kt) {
    const bf16_t* s = Bg + (size_t)(h*128)*K + kt;
    char* d = smB + buf*32768 + h*16384 + dst0;
    gload16(s, d); gload16(s + (size_t)64*K, d + 8192);
  };
  // frag reads: row r at row*128 + ((ks*4+lg)^(r&7))*16; r&7 == lr&7
  const int cs0 = (lg ^ (lr & 7)) << 4;
  const int cs1 = ((4 + lg) ^ (lr & 7)) << 4;

  f32x4 acc[8][4] = {};
  bf16x8 a[4][2], b[4][2];

  // prologue: tile0 all 4 halves; tile1 A0,B0,B1 (A1(1) staged at ph1 of group 0)
  stA(0,0,0); stA(0,1,0); stB(0,0,0); stB(0,1,0);
  stA(1,0,64); stB(1,0,64); stB(1,1,64);
  VMC(6);                      // tile0 landed; A0,B0,B1(1) in flight
  BAR_END;

  const int nt = K >> 6;
  for (int u = 0; u < nt; u++) {
    const int buf = u & 1;
    const char* Ab = smA + buf*32768 + wr*16384 + lr*128;
    const char* Bb = smB + buf*32768 + (wc >> 1)*16384 + ((wc & 1)*64 + lr)*128;
    // ph1: read A(m0-3)+B(n0-1); stage A1(u+1) into buf^1 (A1(u-1) freed at ph3 of u-1)
    RDA03(Ab); RDB01(Bb);
    if (u + 1 < nt) stA(buf^1, 1, (u+1) << 6);
    BAR_MID; MM16(0,0); BAR_END;
    // ph2: read B(n2-3)
    RDB23(Bb);
    BAR_MID; MM16(0,2); BAR_END;
    // ph3: read A(m4-7); stage B halves of u+2 into buf (B(u) freed after ph2)
    RDA47(Ab);
    if (u + 2 < nt) { stB(buf, 0, (u+2) << 6); stB(buf, 1, (u+2) << 6); }
    BAR_MID; MM16(4,0); BAR_END;
    // ph4: stage A0(u+2) (A(u) freed after ph3); checkpoint drains tile u+1
    if (u + 2 < nt) {
      stA(buf, 0, (u+2) << 6);
      BAR_MID; MM16(4,2); VMC(6); BAR_END;
    } else {
      BAR_MID; MM16(4,2); VMC(0); BAR_END;   // tail: ensure last tile fully landed
    }
  }
  // epilogue: C/D layout col=lane&15, row=(lane>>4)*4+j (m89-verified)
  #pragma unroll
  for (int m = 0; m < 8; m++) {
    #pragma unroll
    for (int n = 0; n < 4; n++) {
      const int col = col0 + wc*64 + n*16 + lr;
      const float bv = BIAS ? bias[col] : 0.0f;
      #pragma unroll
      for (int j = 0; j < 4; j++) {
        const int row = row0 + wr*128 + m*16 + lg*4 + j;
        C[(size_t)row*N + col] = (OutT)(acc[m][n][j] + bv);
      }
    }
  }
}

// ======== GEMM 128x128, BK=32, 3-deep LDS pipeline (proven 754 TF) ========
// Column-band XCD map replaces the old row-chunk swizzle (L2 B-panel residency).
template<typename OutT, bool BIAS>
__global__ __launch_bounds__(256, 3) void k_gemm_bt(const bf16_t* __restrict__ A,
                                                    const bf16_t* __restrict__ BT,
                                                    OutT* __restrict__ C,
                                                    const float* __restrict__ bias,
                                                    int M, int N, int K) {
  __shared__ char sm[49152];   // buf b at b*16384: A [128][32] then B [128][32]
  const int tid = threadIdx.x, lane = tid & 63, wave = tid >> 6;
  const int wr = wave >> 1, wc = wave & 1;
  const int lr = lane & 15, lg = lane >> 4;
  const int nbx = N >> 7;
  const int band = nbx >> 3;               // requires nbx % 8 == 0
  const int bid = blockIdx.x;
  const int idx = bid >> 3;
  const int bx = (bid & 7)*band + idx % band;
  const int by = idx / band;
  const int row0 = by << 7, col0 = bx << 7;
  const int sr  = tid >> 2;
  const int sxe = (((tid & 3) ^ ((sr >> 1) & 3)) << 3);
  const bf16_t* Ag = A  + (size_t)(row0 + sr)*K + sxe;
  const bf16_t* Bg = BT + (size_t)(col0 + sr)*K + sxe;
  const int dst0 = wave*1024;
  auto stage = [&](int t) {
    char* base = sm + (t % 3)*16384;
    const bf16_t* a = Ag + t*32;
    const bf16_t* b = Bg + t*32;
    gload16(a,                base + dst0);
    gload16(a + (size_t)64*K, base + 4096  + dst0);
    gload16(b,                base + 8192  + dst0);
    gload16(b + (size_t)64*K, base + 12288 + dst0);
  };
  const int cs   = (lg ^ ((lr >> 1) & 3)) << 4;
  const int arow = (wr*64 + lr)*64;
  const int brow = 8192 + (wc*64 + lr)*64;
  f32x4 acc[4][4] = {};
  stage(0); stage(1);
  const int nt = K >> 5;
  for (int t = 0; t < nt; t++) {
    if (t + 2 < nt)      { stage(t + 2); VMC(8); }
    else if (t + 1 < nt) { VMC(4); }
    else                 { VMC(0); }
    __builtin_amdgcn_s_barrier();
    const char* base = sm + (t % 3)*16384;
    bf16x8 af[4], bb[4];
    #pragma unroll
    for (int m = 0; m < 4; m++) af[m] = *(const bf16x8*)(base + arow + m*1024 + cs);
    #pragma unroll
    for (int n = 0; n < 4; n++) bb[n] = *(const bf16x8*)(base + brow + n*1024 + cs);
    asm volatile("s_waitcnt lgkmcnt(0)" ::: "memory");
    __builtin_amdgcn_sched_barrier(0);
    __builtin_amdgcn_s_setprio(1);
    #pragma unroll
    for (int m = 0; m < 4; m++)
      #pragma unroll
      for (int n = 0; n < 4; n++)
        acc[m][n] = __builtin_amdgcn_mfma_f32_16x16x32_bf16(af[m], bb[n], acc[m][n], 0, 0, 0);
    __builtin_amdgcn_s_setprio(0);
    __builtin_amdgcn_s_barrier();
  }
  #pragma unroll
  for (int m = 0; m < 4; m++) {
    #pragma unroll
    for (int n = 0; n < 4; n++) {
      const int col = col0 + wc*64 + n*16 + lr;
      const float bv = BIAS ? bias[col] : 0.0f;
      #pragma unroll
      for (int j = 0; j < 4; j++) {
        const int row = row0 + wr*64 + m*16 + lg*4 + j;
        C[(size_t)row*N + col] = (OutT)(acc[m][n][j] + bv);
      }
    }
  }
}

// -------- Flash attention tile compute (swapped-operand form) --------
template<bool MASK>
__device__ __forceinline__ void attn_tile(
    int kv0, int wq0, int lr, int lg,
    const char* __restrict__ Kb, const char* __restrict__ Vb, char* __restrict__ Pb,
    const bf16x8 (&aq)[4], f32x4 (&o)[8], float& mrow, float& lsum) {
  const int swz = (lr & 7) << 4;
  f32x4 s[4] = {};
  #pragma unroll
  for (int kd = 0; kd < 4; kd++) {
    bf16x8 ak[4];
    #pragma unroll
    for (int n = 0; n < 4; n++)
      ak[n] = *(const bf16x8*)(Kb + (n*16 + lr)*256 + (((kd*4 + lg) << 4) ^ swz));
    __builtin_amdgcn_s_setprio(1);
    #pragma unroll
    for (int n = 0; n < 4; n++)
      s[n] = __builtin_amdgcn_mfma_f32_16x16x32_bf16(ak[n], aq[kd], s[n], 0, 0, 0);
    __builtin_amdgcn_s_setprio(0);
  }
  if (MASK) {
    const int q = wq0 + lr;
    #pragma unroll
    for (int n = 0; n < 4; n++)
      #pragma unroll
      for (int j = 0; j < 4; j++)
        if (kv0 + n*16 + lg*4 + j > q) s[n][j] = -30000.0f;
  }
  float pmax = fmaxf(
      fmaxf(fmaxf(fmaxf(s[0][0], s[0][1]), fmaxf(s[0][2], s[0][3])),
            fmaxf(fmaxf(s[1][0], s[1][1]), fmaxf(s[1][2], s[1][3]))),
      fmaxf(fmaxf(fmaxf(s[2][0], s[2][1]), fmaxf(s[2][2], s[2][3])),
            fmaxf(fmaxf(s[3][0], s[3][1]), fmaxf(s[3][2], s[3][3]))));
  pmax = fmaxf(pmax, __shfl_xor(pmax, 16));
  pmax = fmaxf(pmax, __shfl_xor(pmax, 32));
  if (!__all(pmax - mrow <= 8.0f)) {       // defer-max (T13)
    const float mnew = fmaxf(mrow, pmax);
    const float corr = exp2f(mrow - mnew);
    mrow = mnew;
    lsum *= corr;
    #pragma unroll
    for (int n2 = 0; n2 < 8; n2++) o[n2] *= corr;
  }
  float rs = 0.0f;
  #pragma unroll
  for (int n = 0; n < 4; n++)
    #pragma unroll
    for (int j = 0; j < 4; j++) {
      float p = exp2f(s[n][j] - mrow);
      s[n][j] = p;
      rs += p;
    }
  rs += __shfl_xor(rs, 16);
  rs += __shfl_xor(rs, 32);
  lsum += rs;
  #pragma unroll
  for (int n = 0; n < 4; n++) {
    bf16x4 pw;
    pw[0] = (__bf16)s[n][0]; pw[1] = (__bf16)s[n][1];
    pw[2] = (__bf16)s[n][2]; pw[3] = (__bf16)s[n][3];
    *(bf16x4*)(Pb + ((lr*128 + n*32 + lg*8) ^ swz)) = pw;
  }
  #pragma unroll
  for (int ks = 0; ks < 2; ks++) {
    bf16x8 pb = *(const bf16x8*)(Pb + ((lr*128 + ks*64 + lg*16) ^ swz));
    __builtin_amdgcn_s_setprio(1);
    #pragma unroll
    for (int n2 = 0; n2 < 8; n2++) {
      bf16x8 av = *(const bf16x8*)(Vb + (n2*16 + lr)*128 + (((ks*4 + lg) << 4) ^ swz));
      o[n2] = __builtin_amdgcn_mfma_f32_16x16x32_bf16(av, pb, o[n2], 0, 0, 0);
    }
    __builtin_amdgcn_s_setprio(0);
  }
}

// -------- Flash attention, causal. 8 waves x 16 q-rows. Flat grid 512. --------
// XCD bh-chunking: XCD x owns 4 whole (b,h) pairs (K+V = 4MB, L2-fit),
// qt descending within chunk (heavy first).
__global__ __launch_bounds__(512, 4) void k_attn(const bf16_t* __restrict__ QKV,
                                                 const bf16_t* __restrict__ Vt,
                                                 bf16_t* __restrict__ O) {
  __shared__ bf16_t Ks[2][64*128];
  __shared__ bf16_t Vs[2][128*64];
  __shared__ bf16_t Pl[8][16*64];
  const int tid = threadIdx.x, lane = tid & 63, wave = tid >> 6;
  const int bidx = blockIdx.x;
  const int xcd = bidx & 7, idx = bidx >> 3;       // idx 0..63
  const int bh  = xcd*4 + (idx & 3);               // 4 (b,h) pairs per XCD
  const int qt  = 15 - (idx >> 2);                 // heavy first
  const int b = bh >> 4, h = bh & 15;
  const int wq0 = qt*128 + wave*16;
  const int lr = lane & 15, lg = lane >> 4;
  char* Pb = (char*)&Pl[wave][0];
  const bf16_t* Q = QKV;
  const bf16_t* K = QKV + F_;

  bf16x8 aq[4];
  #pragma unroll
  for (int kd = 0; kd < 4; kd++)
    aq[kd] = *(const bf16x8*)&Q[(size_t)(b*L_ + wq0 + lr)*QS + h*D_ + kd*32 + lg*8];

  const int kr = tid >> 4, kc = tid & 15;
  const bf16_t* Kg0 = K + (size_t)(b*L_ + kr)*QS + h*D_ + ((kc ^ (kr & 7)) << 3);
  const int vr = tid >> 3, vc = tid & 7;
  const bf16_t* Vg0 = Vt + (size_t)((b*H_ + h)*D_ + vr)*L_ + ((vc ^ (vr & 7)) << 3);

  f32x4 o[8] = {};
  float mrow = -3.0e38f, lsum = 0.0f;
  const int ntb   = 2*qt + 2;
  const int nfull = (wq0 + 1) >> 6;
  const int nmine = ((wq0 + 15) >> 6) + 1;

  {
    char* kb = (char*)&Ks[0][0] + wave*1024;
    char* vb = (char*)&Vs[0][0] + wave*1024;
    gload16(Kg0,                 kb);
    gload16(Kg0 + (size_t)32*QS, kb + 8192);
    gload16(Vg0,                 vb);
    gload16(Vg0 + (size_t)64*L_, vb + 8192);
  }
  __syncthreads();

  int buf = 0;
  for (int t = 0; t < ntb; t++) {
    if (t + 1 < ntb) {
      const int kn = (t+1)*64;
      char* kb = (char*)&Ks[buf^1][0] + wave*1024;
      char* vb = (char*)&Vs[buf^1][0] + wave*1024;
      const bf16_t* kg = Kg0 + (size_t)kn*QS;
      const bf16_t* vg = Vg0 + kn;
      gload16(kg,                 kb);
      gload16(kg + (size_t)32*QS, kb + 8192);
      gload16(vg,                 vb);
      gload16(vg + (size_t)64*L_, vb + 8192);
    }
    const char* Kb = (const char*)&Ks[buf][0];
    const char* Vb = (const char*)&Vs[buf][0];
    if (t < nfull)
      attn_tile<false>(t*64, wq0, lr, lg, Kb, Vb, Pb, aq, o, mrow, lsum);
    else if (t < nmine)
      attn_tile<true >(t*64, wq0, lr, lg, Kb, Vb, Pb, aq, o, mrow, lsum);
    __syncthreads();
    buf ^= 1;
  }
  const float inv = 1.0f / lsum;
  bf16_t* orow = O + (size_t)(b*L_ + wq0 + lr)*F_ + h*D_ + lg*4;
  #pragma unroll
  for (int n2 = 0; n2 < 8; n2++) {
    bf16x4 ov;
    ov[0] = (__bf16)(o[n2][0]*inv); ov[1] = (__bf16)(o[n2][1]*inv);
    ov[2] = (__bf16)(o[n2][2]*inv); ov[3] = (__bf16)(o[n2][3]*inv);
    *(bf16x4*)(orow + n2*16) = ov;
  }
}

extern "C" void kernel_launch(void* const* d_in, const int* in_sizes, int n_in,
                              void* d_out, int out_size, void* d_ws, size_t ws_size,
                              hipStream_t stream) {
  const float* x  = (const float*)d_in[0];
  const float* Wq = (const float*)d_in[1];
  const float* Wk = (const float*)d_in[2];
  const float* Wv = (const float*)d_in[3];
  const float* Wo = (const float*)d_in[4];
  const float* bo = (const float*)d_in[5];
  float* out = (float*)d_out;

  char* ws = (char*)d_ws;
  size_t off = 0;
  auto alloc = [&](size_t bytes) {
    char* p = ws + off;
    off = (off + bytes + 255) & ~(size_t)255;
    return p;
  };
  bf16_t* xb    = (bf16_t*)alloc((size_t)NROW*E_*2);     // x bf16; reused as attn out
  bf16_t* wqkvt = (bf16_t*)alloc((size_t)3*F_*E_*2);     // [Wq^T;Wk^T;Wv^T] bf16
  bf16_t* wot   = (bf16_t*)alloc((size_t)F_*E_*2);       // Wo^T bf16 [E][F]
  float2* sc    = (float2*)alloc((size_t)L_*64*sizeof(float2));
  bf16_t* qkv   = (bf16_t*)alloc((size_t)NROW*QS*2);     // fused QKV [4096][6144]
  bf16_t* vt    = (bf16_t*)alloc((size_t)NROW*F_*2);     // V^T [B][H][D][L]
  bf16_t* ob    = xb;                                    // attn output (xb dead by then)

  const float scale2 = 0.08838834764831845f * 1.44269504088896f;  // 1/sqrt(D)*log2(e)

  // 1. fused prep: convert + 4 weight transposes + sincos (one launch)
  k_prep<<<dim3(25088), 256, 0, stream>>>(x, Wq, Wk, Wv, Wo, xb, wqkvt, wot, sc);

  // 2. fused QKV projection: 256^2 4-phase (384 blocks, column-band XCD map)
  k_gemm256<bf16_t, false><<<dim3((QS/256)*(NROW/256)), 512, 0, stream>>>(
      xb, wqkvt, qkv, nullptr, NROW, QS, E_);

  // 3. fused RoPE(q,k) + V transpose (one launch)
  k_ropetv<<<dim3(24576), 256, 0, stream>>>(qkv, vt, sc, scale2);

  // 4. flash attention (flat 512 blocks, XCD bh-chunked)
  k_attn<<<dim3(512), 512, 0, stream>>>(qkv, vt, ob);

  // 5. output projection + bias (128^2 3-deep, column-band XCD map)
  k_gemm_bt<float, true><<<dim3((E_/128)*(NROW/128)), 256, 0, stream>>>(
      ob, wot, out, bo, NROW, E_, F_);
}